// Round 12
// baseline (38.485 us; speedup 1.0000x reference)
//
#include <hip/hip_runtime.h>
#include <hip/hip_bf16.h>

// bottom (8,256,128,128) f32; w1 (256,1,3,3); a1,w2,b2 (256,)
// out: res (8,256,64,64) ++ pexp (8,256,64,64), f32.  K=3 S=2 P=1 -> 64x64.
// R12 = R11 + exact-once global reads: wave wid loads plane rows
// 8wid..8wid+7 only (union = all 128 rows, no boundary re-read); its last
// row is shared to wave wid+1 through LDS across the existing max barrier.

#define HW 16384       // 128*128
#define N_OUT 8388608  // 8*256*64*64
#define NEG_INF (-__builtin_inff())

__device__ __forceinline__ float hw_log2(float x) { return __builtin_amdgcn_logf(x); }
__device__ __forceinline__ float hw_exp2(float x) { return __builtin_amdgcn_exp2f(x); }
__device__ __forceinline__ float hw_rcp(float x)  { return __builtin_amdgcn_rcpf(x); }

__global__ __launch_bounds__(1024, 8) void fused_ppool_v12(
    const float* __restrict__ bottom,
    const float* __restrict__ w1,   // (256,3,3)
    const float* __restrict__ a1,
    const float* __restrict__ w2,
    const float* __restrict__ b2,
    float* __restrict__ out) {
    __shared__ float smax[16];
    __shared__ float2 brow[16][64]; // wave w's row 8wid+7 (= wave w+1's row 0)

    const int t    = threadIdx.x;
    const int wid  = t >> 6;        // 0..15
    const int lane = t & 63;
    const int bc   = blockIdx.x;    // one plane per block
    const int c    = bc & 255;

    const float* plane = bottom + (size_t)bc * HW;

    float wk[9];
    #pragma unroll
    for (int k = 0; k < 9; ++k) wk[k] = w1[c * 9 + k];   // block-uniform
    const float slope = a1[c];
    const float ww2   = w2[c];
    const float bb2   = b2[c];

    // Wave wid owns output rows ho0..ho0+3 -> window rows 8wid-1 .. 8wid+7.
    // Rows 8wid..8wid+7 loaded from global (r=1..8); row 8wid-1 via LDS.
    const int ho0   = wid * 4;
    const int hbase = 2 * ho0 - 1;  // 8wid - 1

    float lx0[9], lx1[9], lxm[9];   // log2(relu(x)) at cols 2wo, 2wo+1, 2wo-1
    float A[4];
    A[0] = A[1] = A[2] = A[3] = 0.f;
    float mx = 0.f;

    // ---- Load phase: 8 global row loads; max/logs/conv as data arrives ----
    #pragma unroll
    for (int r = 1; r < 9; ++r) {
        const int hi = hbase + r;   // 8wid + (r-1), always in [0,127]
        float2 v = *reinterpret_cast<const float2*>(plane + hi * 128 + lane * 2);
        const float a = v.x, b = v.y;
        if (r == 8) brow[wid][lane] = v;        // share with wave wid+1
        mx = fmaxf(mx, fmaxf(fabsf(a), fabsf(b)));
        float xm = __shfl_up(b, 1, 64);
        if (lane == 0) xm = 0.f;                // zero pad col -1
        #pragma unroll
        for (int rr = 0; rr < 4; ++rr) {
            const int k = r - 2 * rr;
            if (k >= 0 && k <= 2)
                A[rr] += wk[3 * k] * xm + wk[3 * k + 1] * a + wk[3 * k + 2] * b;
        }
        lx0[r] = hw_log2(fmaxf(a, 0.f));        // log2(0) = -inf -> exp2 = 0
        lx1[r] = hw_log2(fmaxf(b, 0.f));
        float sl = __shfl_up(lx1[r], 1, 64);
        lxm[r] = (lane == 0) ? NEG_INF : sl;
    }

    // ---- Plane max reduce (also publishes brow) ----
    #pragma unroll
    for (int off = 32; off; off >>= 1)
        mx = fmaxf(mx, __shfl_down(mx, off, 64));
    if (lane == 0) smax[wid] = mx;
    __syncthreads();
    float mm = smax[0];
    #pragma unroll
    for (int k = 1; k < 16; ++k) mm = fmaxf(mm, smax[k]);
    const float inv_m = hw_rcp(mm + 1.0f);

    // ---- Row 0 (8wid-1): from previous wave's LDS slot, or zero pad ----
    {
        float a = 0.f, b = 0.f;
        if (wid > 0) { float2 v = brow[wid - 1][lane]; a = v.x; b = v.y; }
        float xm = __shfl_up(b, 1, 64);
        if (lane == 0) xm = 0.f;
        A[0] += wk[0] * xm + wk[1] * a + wk[2] * b;
        lx0[0] = hw_log2(fmaxf(a, 0.f));
        lx1[0] = hw_log2(fmaxf(b, 0.f));
        float sl = __shfl_up(lx1[0], 1, 64);
        lxm[0] = (lane == 0) ? NEG_INF : sl;
    }

    float* outres = out + (size_t)bc * 4096;
    float* outp   = out + N_OUT + (size_t)bc * 4096;

    // ---- p-dependent tail: 9 exp2 + finals per output ----
    #pragma unroll
    for (int rr = 0; rr < 4; ++rr) {
        float v = A[rr] * inv_m;                // conv(x/m)
        v = v > 0.f ? v : slope * v;            // PReLU
        float p = v * ww2 + bb2;                // 1x1 dw conv + bias
        p = fminf(fmaxf(p, 1.0f), 110.0f);      // hardtanh

        float s0 = 0.f, s1 = 0.f;               // 2-acc ILP on trans pipe
        #pragma unroll
        for (int k = 0; k < 3; ++k) {
            const int r = 2 * rr + k;
            s0 += hw_exp2(p * lxm[r]);
            s1 += hw_exp2(p * lx0[r]);
            s0 += hw_exp2(p * lx1[r]);
        }
        float mp  = (s0 + s1) * (1.0f / 9.0f) + 1e-12f;
        float res = hw_exp2(hw_log2(mp) * hw_rcp(p));

        const int ho = ho0 + rr;
        __builtin_nontemporal_store(res, &outres[ho * 64 + lane]);
        __builtin_nontemporal_store(p,   &outp  [ho * 64 + lane]);
    }
}

extern "C" void kernel_launch(void* const* d_in, const int* in_sizes, int n_in,
                              void* d_out, int out_size, void* d_ws, size_t ws_size,
                              hipStream_t stream) {
    const float* bottom = (const float*)d_in[0];
    const float* w1     = (const float*)d_in[1];
    const float* a1     = (const float*)d_in[2];
    const float* w2     = (const float*)d_in[3];
    const float* b2     = (const float*)d_in[4];
    float* out = (float*)d_out;

    fused_ppool_v12<<<2048, 1024, 0, stream>>>(bottom, w1, a1, w2, b2, out);
}

// Round 13
// 36.315 us; speedup vs baseline: 1.0597x; 1.0597x over previous
//
#include <hip/hip_runtime.h>
#include <hip/hip_bf16.h>

// bottom (8,256,128,128) f32; w1 (256,1,3,3); a1,w2,b2 (256,)
// out: res (8,256,64,64) ++ pexp (8,256,64,64), f32.  K=3 S=2 P=1 -> 64x64.
// R13 = exact revert to R11 (best: 35.72 us).
//   - one 1024-thr block per plane (2 blocks/CU, 32 waves/CU, LDS = 64 B)
//   - direct-global float2 row loads; abs-max, log2(relu(x)), conv partials,
//     and left-neighbor shuffles ALL computed during the load phase
//   - single barrier for the plane max; post-barrier only the p-dependent
//     exp2 tail; non-temporal output stores.
// R12's boundary-dedup regressed (+2.8us serial tail): boundary re-reads
// are L1-absorbed, NOT HBM traffic. Do not re-add.

#define HW 16384       // 128*128
#define N_OUT 8388608  // 8*256*64*64
#define NEG_INF (-__builtin_inff())

__device__ __forceinline__ float hw_log2(float x) { return __builtin_amdgcn_logf(x); }
__device__ __forceinline__ float hw_exp2(float x) { return __builtin_amdgcn_exp2f(x); }
__device__ __forceinline__ float hw_rcp(float x)  { return __builtin_amdgcn_rcpf(x); }

__global__ __launch_bounds__(1024, 8) void fused_ppool_v13(
    const float* __restrict__ bottom,
    const float* __restrict__ w1,   // (256,3,3)
    const float* __restrict__ a1,
    const float* __restrict__ w2,
    const float* __restrict__ b2,
    float* __restrict__ out) {
    __shared__ float smax[16];

    const int t    = threadIdx.x;
    const int wid  = t >> 6;        // 0..15
    const int lane = t & 63;
    const int bc   = blockIdx.x;    // one plane per block
    const int c    = bc & 255;

    const float* plane = bottom + (size_t)bc * HW;

    float wk[9];
    #pragma unroll
    for (int k = 0; k < 9; ++k) wk[k] = w1[c * 9 + k];   // block-uniform
    const float slope = a1[c];
    const float ww2   = w2[c];
    const float bb2   = b2[c];

    // Wave wid owns output rows ho0..ho0+3 -> input rows 2*ho0-1 .. 2*ho0+7.
    const int ho0   = wid * 4;
    const int hbase = 2 * ho0 - 1;  // -1 only for wid==0, r==0

    float lx0[9], lx1[9], lxm[9];   // log2(relu(x)) at cols 2wo, 2wo+1, 2wo-1
    float A[4];                     // conv accumulators for 4 output rows
    A[0] = A[1] = A[2] = A[3] = 0.f;
    float mx = 0.f;

    // ---- Load phase: 9 row loads; max/logs/conv/shuffles as data arrives ----
    #pragma unroll
    for (int r = 0; r < 9; ++r) {
        const int hi = hbase + r;   // wave-uniform
        float a = 0.f, b = 0.f;
        if (hi >= 0) {
            float2 v = *reinterpret_cast<const float2*>(plane + hi * 128 + lane * 2);
            a = v.x; b = v.y;
        }
        mx = fmaxf(mx, fmaxf(fabsf(a), fabsf(b)));
        float xm = __shfl_up(b, 1, 64);
        if (lane == 0) xm = 0.f;    // zero pad col -1
        #pragma unroll
        for (int rr = 0; rr < 4; ++rr) {
            const int k = r - 2 * rr;
            if (k >= 0 && k <= 2)
                A[rr] += wk[3 * k] * xm + wk[3 * k + 1] * a + wk[3 * k + 2] * b;
        }
        lx0[r] = hw_log2(fmaxf(a, 0.f));    // log2(0) = -inf -> exp2 = 0
        lx1[r] = hw_log2(fmaxf(b, 0.f));
        float sl = __shfl_up(lx1[r], 1, 64);
        lxm[r] = (lane == 0) ? NEG_INF : sl;   // pre-barrier (m-independent)
    }

    // ---- Plane max reduce (the only cross-wave dependency) ----
    #pragma unroll
    for (int off = 32; off; off >>= 1)
        mx = fmaxf(mx, __shfl_down(mx, off, 64));
    if (lane == 0) smax[wid] = mx;
    __syncthreads();
    float mm = smax[0];
    #pragma unroll
    for (int k = 1; k < 16; ++k) mm = fmaxf(mm, smax[k]);
    const float inv_m = hw_rcp(mm + 1.0f);

    float* outres = out + (size_t)bc * 4096;
    float* outp   = out + N_OUT + (size_t)bc * 4096;

    // ---- p-dependent tail: 9 exp2 + finals per output ----
    #pragma unroll
    for (int rr = 0; rr < 4; ++rr) {
        float v = A[rr] * inv_m;                // conv(x/m)
        v = v > 0.f ? v : slope * v;            // PReLU
        float p = v * ww2 + bb2;                // 1x1 dw conv + bias
        p = fminf(fmaxf(p, 1.0f), 110.0f);      // hardtanh

        float s0 = 0.f, s1 = 0.f;               // 2-acc ILP on trans pipe
        #pragma unroll
        for (int k = 0; k < 3; ++k) {
            const int r = 2 * rr + k;
            s0 += hw_exp2(p * lxm[r]);
            s1 += hw_exp2(p * lx0[r]);
            s0 += hw_exp2(p * lx1[r]);
        }
        float mp  = (s0 + s1) * (1.0f / 9.0f) + 1e-12f;
        float res = hw_exp2(hw_log2(mp) * hw_rcp(p));

        const int ho = ho0 + rr;
        __builtin_nontemporal_store(res, &outres[ho * 64 + lane]);
        __builtin_nontemporal_store(p,   &outp  [ho * 64 + lane]);
    }
}

extern "C" void kernel_launch(void* const* d_in, const int* in_sizes, int n_in,
                              void* d_out, int out_size, void* d_ws, size_t ws_size,
                              hipStream_t stream) {
    const float* bottom = (const float*)d_in[0];
    const float* w1     = (const float*)d_in[1];
    const float* a1     = (const float*)d_in[2];
    const float* w2     = (const float*)d_in[3];
    const float* b2     = (const float*)d_in[4];
    float* out = (float*)d_out;

    fused_ppool_v13<<<2048, 1024, 0, stream>>>(bottom, w1, a1, w2, b2, out);
}